// Round 3
// baseline (154.421 us; speedup 1.0000x reference)
//
#include <hip/hip_runtime.h>
#include <math.h>

#define NBATCH 4
#define NV 9
#define DM 64
#define DS 16
// H = W = 32, image = 1024 pixels

__device__ __forceinline__ float softplus_f(float x) {
    return (x > 20.f) ? x : log1pf(__expf(x));
}

// ---------------------------------------------------------------------------
// Kernel 1: fused circular 3x3 convs. 96 "output channels":
//   co in [0,64)  -> delta conv (+bias +dt, softplus)
//   co in [64,80) -> B conv
//   co in [80,96) -> C conv
// Grid: 4(b) * 96(co) = 384 blocks, 256 threads.
// Each thread: 4 consecutive pixels of one row (row = tid>>3, w0 = (tid&7)*4).
// u loads: 1 float4 + 2 scalars per tap-row; weights are block-uniform s_loads
// reused across the 4 pixels.
// ---------------------------------------------------------------------------
__global__ __launch_bounds__(256) void conv_kernel(
    const float* __restrict__ u, const float* __restrict__ wd,
    const float* __restrict__ bd, const float* __restrict__ wb,
    const float* __restrict__ wc, const float* __restrict__ dtp,
    float* __restrict__ delta_out, float* __restrict__ Bv_out,
    float* __restrict__ Cv_out)
{
    int bx = blockIdx.x;
    int co = bx % 96;
    int b  = bx / 96;
    int tid = threadIdx.x;
    int row = tid >> 3;
    int w0  = (tid & 7) << 2;

    const float* wbase = (co < 64) ? (wd + (size_t)co * 576)
                       : (co < 80) ? (wb + (size_t)(co - 64) * 576)
                                   : (wc + (size_t)(co - 80) * 576);

    int hm = (row + 31) & 31, hp = (row + 1) & 31;
    int wl = (w0 + 31) & 31;   // col w0-1 (wrapped)
    int wr = (w0 + 4) & 31;    // col w0+4 (wrapped)
    const float* ub = u + (size_t)b * 65536;

    float a0 = 0.f, a1 = 0.f, a2 = 0.f, a3 = 0.f;
    #pragma unroll 4
    for (int ci = 0; ci < 64; ++ci) {
        const float* base = ub + ci * 1024;
        const float* wq = wbase + ci * 9;
        #pragma unroll
        for (int r = 0; r < 3; ++r) {
            int rr = (r == 0) ? hm : (r == 1) ? row : hp;
            const float* rp = base + rr * 32;
            float4 v = *(const float4*)(rp + w0);
            float L = rp[wl], R = rp[wr];
            float k0 = wq[r * 3 + 0], k1 = wq[r * 3 + 1], k2 = wq[r * 3 + 2];
            a0 = fmaf(k0, L,   fmaf(k1, v.x, fmaf(k2, v.y, a0)));
            a1 = fmaf(k0, v.x, fmaf(k1, v.y, fmaf(k2, v.z, a1)));
            a2 = fmaf(k0, v.y, fmaf(k1, v.z, fmaf(k2, v.w, a2)));
            a3 = fmaf(k0, v.z, fmaf(k1, v.w, fmaf(k2, R,   a3)));
        }
    }

    int pix = row * 32 + w0;
    if (co < 64) {
        float bias = bd[co] + dtp[0];
        float4 o;
        o.x = softplus_f(a0 + bias);
        o.y = softplus_f(a1 + bias);
        o.z = softplus_f(a2 + bias);
        o.w = softplus_f(a3 + bias);
        *(float4*)(delta_out + (((size_t)b * 64 + co) << 10) + pix) = o;
    } else if (co < 80) {
        *(float4*)(Bv_out + (((size_t)b * 16 + (co - 64)) << 10) + pix) =
            make_float4(a0, a1, a2, a3);
    } else {
        *(float4*)(Cv_out + (((size_t)b * 16 + (co - 80)) << 10) + pix) =
            make_float4(a0, a1, a2, a3);
    }
}

// ---------------------------------------------------------------------------
// Kernel 2: state update + y reduction. One thread per (b, i, c, 4 pixels).
// Grid: 4(b)*9(i)*64(c) = 2304 blocks, 256 threads, 4 px/thread -> all f4.
// The x-roll (vx=+-1) is realigned with one __shfl within the 8-lane row
// group (circular wrap of the roll == wrap of the lane group).
// ---------------------------------------------------------------------------
__global__ __launch_bounds__(256) void scan_kernel(
    const float* __restrict__ u, const float* __restrict__ s_prev,
    const float* __restrict__ logA, const float* __restrict__ Dp,
    const float* __restrict__ delta_in, const float* __restrict__ Bv,
    const float* __restrict__ Cv,
    float* __restrict__ y_out, float* __restrict__ s_next)
{
    int bx = blockIdx.x;
    int c  = bx & 63;
    int bi9 = bx >> 6;          // b*9 + i
    int i  = bi9 % 9;
    int b  = bi9 / 9;

    int tid = threadIdx.x;
    int pix0 = tid << 2;        // 4 consecutive pixels
    int h  = pix0 >> 5;
    int vx = i / 3 - 1;
    int vy = i % 3 - 1;
    int hh = (h + vy + 32) & 31;

    int lane = tid & 63;
    int lnext = (lane & ~7) | ((lane + 1) & 7);
    int lprev = (lane & ~7) | ((lane + 7) & 7);

    size_t ubase = (((size_t)b * 64 + c) << 10) + pix0;
    float4 u4 = *(const float4*)(u + ubase);
    float4 d4 = *(const float4*)(delta_in + ubase);
    float dk = Dp[c];
    float4 y4 = make_float4(u4.x * dk, u4.y * dk, u4.z * dk, u4.w * dk);

    size_t chan = ((size_t)bi9 * 64 + c) * 16;
    const float* sp_row = s_prev + (chan << 10) + hh * 32;   // + n*1024 + cols
    float*       sn_px  = s_next + (chan << 10) + pix0;
    const float* bvp = Bv + (((size_t)b * 16) << 10) + pix0;
    const float* cvp = Cv + (((size_t)b * 16) << 10) + pix0;
    const float* la  = logA + c * 16;
    int w0 = pix0 & 31;

    #pragma unroll 4
    for (int n = 0; n < 16; ++n) {
        float A  = -__expf(la[n]);                 // block-uniform
        float rA = __builtin_amdgcn_rcpf(A);

        float4 ab;
        ab.x = __expf(d4.x * A);
        ab.y = __expf(d4.y * A);
        ab.z = __expf(d4.z * A);
        ab.w = __expf(d4.w * A);

        float4 b4 = *(const float4*)(bvp + ((size_t)n << 10));
        float4 c4 = *(const float4*)(cvp + ((size_t)n << 10));

        float4 bu;
        bu.x = (ab.x - 1.f) * rA * b4.x * u4.x;
        bu.y = (ab.y - 1.f) * rA * b4.y * u4.y;
        bu.z = (ab.z - 1.f) * rA * b4.z * u4.z;
        bu.w = (ab.w - 1.f) * rA * b4.w * u4.w;

        float4 f = *(const float4*)(sp_row + ((size_t)n << 10) + w0);
        float4 s4;
        if (vx == 0) {
            s4 = f;
        } else if (vx > 0) {
            float t = __shfl(f.x, lnext);
            s4 = make_float4(f.y, f.z, f.w, t);
        } else {
            float t = __shfl(f.w, lprev);
            s4 = make_float4(t, f.x, f.y, f.z);
        }

        float4 sn;
        sn.x = fmaf(ab.x, s4.x, bu.x);
        sn.y = fmaf(ab.y, s4.y, bu.y);
        sn.z = fmaf(ab.z, s4.z, bu.z);
        sn.w = fmaf(ab.w, s4.w, bu.w);
        *(float4*)(sn_px + ((size_t)n << 10)) = sn;

        y4.x = fmaf(sn.x, c4.x, y4.x);
        y4.y = fmaf(sn.y, c4.y, y4.y);
        y4.z = fmaf(sn.z, c4.z, y4.z);
        y4.w = fmaf(sn.w, c4.w, y4.w);
    }
    *(float4*)(y_out + (((size_t)bi9 * 64 + c) << 10) + pix0) = y4;
}

extern "C" void kernel_launch(void* const* d_in, const int* in_sizes, int n_in,
                              void* d_out, int out_size, void* d_ws, size_t ws_size,
                              hipStream_t stream) {
    const float* u      = (const float*)d_in[0];
    const float* s_prev = (const float*)d_in[1];
    const float* wd     = (const float*)d_in[2];
    const float* bd     = (const float*)d_in[3];
    const float* wb     = (const float*)d_in[4];
    const float* wc     = (const float*)d_in[5];
    const float* logA   = (const float*)d_in[6];
    const float* Dp     = (const float*)d_in[7];
    const float* dtp    = (const float*)d_in[8];

    float* ws    = (float*)d_ws;
    float* delta = ws;                 // 4*64*1024   = 262144 floats
    float* Bv    = ws + 262144;        // 4*16*1024   =  65536 floats
    float* Cv    = ws + 327680;        // 4*16*1024   =  65536 floats

    float* y_out  = (float*)d_out;                            // 4*9*64*1024
    float* s_next = y_out + (size_t)NBATCH * NV * DM * 1024;  // 4*9*64*16*1024

    conv_kernel<<<dim3(4 * 96), dim3(256), 0, stream>>>(
        u, wd, bd, wb, wc, dtp, delta, Bv, Cv);
    scan_kernel<<<dim3(4 * 9 * 64), dim3(256), 0, stream>>>(
        u, s_prev, logA, Dp, delta, Bv, Cv, y_out, s_next);
}

// Round 4
// 102.011 us; speedup vs baseline: 1.5138x; 1.5138x over previous
//
#include <hip/hip_runtime.h>
#include <math.h>

#define NBATCH 4
#define NV 9
#define DM 64
#define DS 16
// H = W = 32, image = 1024 pixels

__device__ __forceinline__ float softplus_f(float x) {
    return (x > 20.f) ? x : log1pf(__expf(x));
}

__device__ __forceinline__ void nt_store_f2(float* p, float x, float y) {
    unsigned long long v = (unsigned long long)__float_as_uint(x)
                         | ((unsigned long long)__float_as_uint(y) << 32);
    __builtin_nontemporal_store(v, (unsigned long long*)p);
}

// ---------------------------------------------------------------------------
// Kernel 1: fused circular 3x3 convs, ci split 4-ways inside the block.
// Grid: 4(b) * 96(co) * 4(ht) = 1536 blocks, 256 threads.
//   wave w (= tid>>6) handles ci in [w*16, w*16+16)  (wave-uniform chunk)
//   pxt = tid & 63 -> 4 consecutive pixels of one row in the 8-row tile.
// Partials reduced through LDS; epilogue fused (bias+softplus for delta).
// ---------------------------------------------------------------------------
__global__ __launch_bounds__(256) void conv_kernel(
    const float* __restrict__ u, const float* __restrict__ wd,
    const float* __restrict__ bd, const float* __restrict__ wb,
    const float* __restrict__ wc, const float* __restrict__ dtp,
    float* __restrict__ delta_out, float* __restrict__ Bv_out,
    float* __restrict__ Cv_out)
{
    int bx = blockIdx.x;
    int ht = bx & 3;
    int co = (bx >> 2) % 96;
    int b  = bx / 384;
    int tid = threadIdx.x;
    int chunk = __builtin_amdgcn_readfirstlane(tid >> 6);  // wave-uniform -> SGPR
    int pxt = tid & 63;
    int row = ht * 8 + (pxt >> 3);
    int w0  = (pxt & 7) << 2;

    const float* wbase = (co < 64) ? (wd + (size_t)co * 576)
                       : (co < 80) ? (wb + (size_t)(co - 64) * 576)
                                   : (wc + (size_t)(co - 80) * 576);

    int hm = (row + 31) & 31, hp = (row + 1) & 31;
    int wl = (w0 + 31) & 31;   // col w0-1 (wrapped)
    int wr = (w0 + 4) & 31;    // col w0+4 (wrapped)
    const float* ub = u + (size_t)b * 65536 + (size_t)(chunk << 4) * 1024;
    const float* wq0 = wbase + (size_t)(chunk << 4) * 9;

    float a0 = 0.f, a1 = 0.f, a2 = 0.f, a3 = 0.f;
    #pragma unroll 4
    for (int j = 0; j < 16; ++j) {
        const float* base = ub + j * 1024;
        const float* wq = wq0 + j * 9;
        #pragma unroll
        for (int r = 0; r < 3; ++r) {
            int rr = (r == 0) ? hm : (r == 1) ? row : hp;
            const float* rp = base + rr * 32;
            float4 v = *(const float4*)(rp + w0);
            float L = rp[wl], R = rp[wr];
            float k0 = wq[r * 3 + 0], k1 = wq[r * 3 + 1], k2 = wq[r * 3 + 2];
            a0 = fmaf(k0, L,   fmaf(k1, v.x, fmaf(k2, v.y, a0)));
            a1 = fmaf(k0, v.x, fmaf(k1, v.y, fmaf(k2, v.z, a1)));
            a2 = fmaf(k0, v.y, fmaf(k1, v.z, fmaf(k2, v.w, a2)));
            a3 = fmaf(k0, v.z, fmaf(k1, v.w, fmaf(k2, R,   a3)));
        }
    }

    __shared__ float4 part[4][64];
    part[chunk][pxt] = make_float4(a0, a1, a2, a3);
    __syncthreads();

    if (tid < 64) {
        float4 p0 = part[0][tid], p1 = part[1][tid];
        float4 p2 = part[2][tid], p3 = part[3][tid];
        float s0 = p0.x + p1.x + p2.x + p3.x;
        float s1 = p0.y + p1.y + p2.y + p3.y;
        float s2 = p0.z + p1.z + p2.z + p3.z;
        float s3 = p0.w + p1.w + p2.w + p3.w;
        int prow = ht * 8 + (tid >> 3);
        int pw   = (tid & 7) << 2;
        int pix  = prow * 32 + pw;
        if (co < 64) {
            float bias = bd[co] + dtp[0];
            float4 o;
            o.x = softplus_f(s0 + bias);
            o.y = softplus_f(s1 + bias);
            o.z = softplus_f(s2 + bias);
            o.w = softplus_f(s3 + bias);
            *(float4*)(delta_out + (((size_t)b * 64 + co) << 10) + pix) = o;
        } else if (co < 80) {
            *(float4*)(Bv_out + (((size_t)b * 16 + (co - 64)) << 10) + pix) =
                make_float4(s0, s1, s2, s3);
        } else {
            *(float4*)(Cv_out + (((size_t)b * 16 + (co - 80)) << 10) + pix) =
                make_float4(s0, s1, s2, s3);
        }
    }
}

// ---------------------------------------------------------------------------
// Kernel 2: state update + y reduction. One thread per (b, i, c, 2 pixels).
// Grid: 4(b)*9(i)*64(c)*2(half) = 4608 blocks, 256 threads -> 18432 waves.
// A[n], 1/A[n] are block-uniform (c fixed) -> 16-entry LDS table.
// x-roll realigned with one __shfl in the 16-lane row group.
// s_next / y_out written non-temporally (never re-read; keeps s_prev in L3).
// ---------------------------------------------------------------------------
__global__ __launch_bounds__(256) void scan_kernel(
    const float* __restrict__ u, const float* __restrict__ s_prev,
    const float* __restrict__ logA, const float* __restrict__ Dp,
    const float* __restrict__ delta_in, const float* __restrict__ Bv,
    const float* __restrict__ Cv,
    float* __restrict__ y_out, float* __restrict__ s_next)
{
    int bx = blockIdx.x;
    int half = bx & 1;
    int c  = (bx >> 1) & 63;
    int bi9 = bx >> 7;          // b*9 + i
    int i  = bi9 % 9;
    int b  = bi9 / 9;

    int tid = threadIdx.x;
    int pix0 = ((half << 8) + tid) << 1;   // 2 consecutive pixels
    int h  = pix0 >> 5;
    int w0 = pix0 & 31;
    int vx = i / 3 - 1;
    int vy = i % 3 - 1;
    int hh = (h + vy + 32) & 31;

    int lane = tid & 63;
    int lnext = (lane & ~15) | ((lane + 1) & 15);
    int lprev = (lane & ~15) | ((lane + 15) & 15);

    __shared__ float sA[16], srA[16];
    if (tid < 16) {
        float A = -__expf(logA[c * 16 + tid]);
        sA[tid]  = A;
        srA[tid] = __builtin_amdgcn_rcpf(A);
    }
    __syncthreads();

    size_t ubase = (((size_t)b * 64 + c) << 10) + pix0;
    float2 u2 = *(const float2*)(u + ubase);
    float2 d2 = *(const float2*)(delta_in + ubase);
    float dk = Dp[c];
    float yx = u2.x * dk, yy = u2.y * dk;

    size_t chan = ((size_t)bi9 * 64 + c) * 16;
    const float* sp_row = s_prev + (chan << 10) + hh * 32 + w0;
    float*       sn_px  = s_next + (chan << 10) + pix0;
    const float* bvp = Bv + (((size_t)b * 16) << 10) + pix0;
    const float* cvp = Cv + (((size_t)b * 16) << 10) + pix0;

    #pragma unroll 4
    for (int n = 0; n < 16; ++n) {
        float A  = sA[n];
        float rA = srA[n];

        float2 b2 = *(const float2*)(bvp + ((size_t)n << 10));
        float2 c2 = *(const float2*)(cvp + ((size_t)n << 10));
        float2 f  = *(const float2*)(sp_row + ((size_t)n << 10));

        float abx = __expf(d2.x * A);
        float aby = __expf(d2.y * A);
        float bux = (abx - 1.f) * rA * b2.x * u2.x;
        float buy = (aby - 1.f) * rA * b2.y * u2.y;

        float sx, sy;
        if (vx == 0) {
            sx = f.x; sy = f.y;
        } else if (vx > 0) {
            sx = f.y; sy = __shfl(f.x, lnext);
        } else {
            sx = __shfl(f.y, lprev); sy = f.x;
        }

        float snx = fmaf(abx, sx, bux);
        float sny = fmaf(aby, sy, buy);
        nt_store_f2(sn_px + ((size_t)n << 10), snx, sny);

        yx = fmaf(snx, c2.x, yx);
        yy = fmaf(sny, c2.y, yy);
    }
    nt_store_f2(y_out + (((size_t)bi9 * 64 + c) << 10) + pix0, yx, yy);
}

extern "C" void kernel_launch(void* const* d_in, const int* in_sizes, int n_in,
                              void* d_out, int out_size, void* d_ws, size_t ws_size,
                              hipStream_t stream) {
    const float* u      = (const float*)d_in[0];
    const float* s_prev = (const float*)d_in[1];
    const float* wd     = (const float*)d_in[2];
    const float* bd     = (const float*)d_in[3];
    const float* wb     = (const float*)d_in[4];
    const float* wc     = (const float*)d_in[5];
    const float* logA   = (const float*)d_in[6];
    const float* Dp     = (const float*)d_in[7];
    const float* dtp    = (const float*)d_in[8];

    float* ws    = (float*)d_ws;
    float* delta = ws;                 // 4*64*1024   = 262144 floats
    float* Bv    = ws + 262144;        // 4*16*1024   =  65536 floats
    float* Cv    = ws + 327680;        // 4*16*1024   =  65536 floats

    float* y_out  = (float*)d_out;                            // 4*9*64*1024
    float* s_next = y_out + (size_t)NBATCH * NV * DM * 1024;  // 4*9*64*16*1024

    conv_kernel<<<dim3(4 * 96 * 4), dim3(256), 0, stream>>>(
        u, wd, bd, wb, wc, dtp, delta, Bv, Cv);
    scan_kernel<<<dim3(4 * 9 * 64 * 2), dim3(256), 0, stream>>>(
        u, s_prev, logA, Dp, delta, Bv, Cv, y_out, s_next);
}